// Round 7
// baseline (2214.681 us; speedup 1.0000x reference)
//
#include <hip/hip_runtime.h>
#include <hip/hip_cooperative_groups.h>

namespace cg = cooperative_groups;

#define NPOIS 100000
#define NHYP  50000
#define NNZE  1600000
#define DIM   256

// coarse bucket shifts: 782 buckets for both matrices
#define SH_TAR 6    // 64 rows/bucket
#define SH_SRC 7    // 128 rows/bucket
#define NBUCK 782
#define CHUNK 6250  // 256 chunks * 6250 = NNZE exactly

typedef unsigned int uint;

// exact f32 value of the reference's dropout scale 1/(1-0.3)
#define DROP_C ((float)(1.0 / (1.0 - 0.3)))

// ---- workspace byte offsets (all 16B-aligned; total w/ pois_h = 154.2 MB) ----
#define OFF_EPT   0
#define OFF_EPS   6400000
#define OFF_RPT   12800000
#define OFF_RPS   13000064
#define OFF_MISC  13400128
#define OFF_MSG   13432896
#define OFF_EMB   39032896
#define OFF_BITS1 90232896
#define OFF_BITS2 96632896
#define OFF_POISH 103032896
#define NEED_BITS 103032896
#define NEED_FULL 154232896

// ---------- bf16 helpers (RNE) ----------
__device__ __forceinline__ uint pack_bf16(float a, float b) {
    uint ua = __float_as_uint(a); ua += 0x7fffu + ((ua >> 16) & 1u);
    uint ub = __float_as_uint(b); ub += 0x7fffu + ((ub >> 16) & 1u);
    return (ua >> 16) | (ub & 0xffff0000u);
}
__device__ __forceinline__ float4 unpack_h(uint2 u) {
    return make_float4(__uint_as_float(u.x << 16), __uint_as_float(u.x & 0xffff0000u),
                       __uint_as_float(u.y << 16), __uint_as_float(u.y & 0xffff0000u));
}

// ---------- gather cores (full-D, batched depth-8, packed 4-B edges) ----------
#define GCH 8

__device__ __forceinline__ float4 gather_h(
    const int* rp, const uint* ep, const uint2* dh, int row, int lane)
{
    int s = rp[row], e = rp[row + 1];
    float4 acc = {0.f, 0.f, 0.f, 0.f};
    for (int k = s; k < e; k += GCH) {
        uint ev[GCH];
#pragma unroll
        for (int j = 0; j < GCH; ++j)
            ev[j] = (k + j < e) ? ep[k + j] : 0u;
        uint2 x[GCH];
#pragma unroll
        for (int j = 0; j < GCH; ++j)
            x[j] = dh[(size_t)(ev[j] >> 15) * (DIM / 4) + lane];
#pragma unroll
        for (int j = 0; j < GCH; ++j) {
            float vv = __uint_as_float((ev[j] & 0x7fffu) << 16);
            acc.x += vv * __uint_as_float(x[j].x << 16);
            acc.y += vv * __uint_as_float(x[j].x & 0xffff0000u);
            acc.z += vv * __uint_as_float(x[j].y << 16);
            acc.w += vv * __uint_as_float(x[j].y & 0xffff0000u);
        }
    }
    return acc;
}

__device__ __forceinline__ float4 gather_f(
    const int* rp, const uint* ep, const float4* d4, int row, int lane)
{
    int s = rp[row], e = rp[row + 1];
    float4 acc = {0.f, 0.f, 0.f, 0.f};
    for (int k = s; k < e; k += GCH) {
        uint ev[GCH];
#pragma unroll
        for (int j = 0; j < GCH; ++j)
            ev[j] = (k + j < e) ? ep[k + j] : 0u;
        float4 x[GCH];
#pragma unroll
        for (int j = 0; j < GCH; ++j)
            x[j] = d4[(size_t)(ev[j] >> 15) * (DIM / 4) + lane];
#pragma unroll
        for (int j = 0; j < GCH; ++j) {
            float vv = __uint_as_float((ev[j] & 0x7fffu) << 16);
            acc.x += vv * x[j].x;
            acc.y += vv * x[j].y;
            acc.z += vv * x[j].z;
            acc.w += vv * x[j].w;
        }
    }
    return acc;
}

// drop-mask bits: word = row*8 + (lane>>3), bits (lane&7)*4 .. +3
__device__ __forceinline__ float4 drop4(const uint* bm, int row, int lane)
{
    uint m = bm[(size_t)row * 8 + (lane >> 3)] >> ((lane & 7) * 4);
    return make_float4((m & 1u) ? DROP_C : 0.f, (m & 2u) ? DROP_C : 0.f,
                       (m & 4u) ? DROP_C : 0.f, (m & 8u) ? DROP_C : 0.f);
}

// =====================================================================
// MEGA: whole pipeline in one cooperative launch (8 grid syncs)
// =====================================================================
__global__ __launch_bounds__(256) void mega(
    const float* pois, const float* tar_vals, const float* src_vals,
    const float* attn, const float* drop1, const float* drop2,
    const int* tar_rows, const int* tar_cols,
    const int* src_rows, const int* src_cols,
    float4* out, char* ws, int full, int have_bits)
{
    cg::grid_group grid = cg::this_grid();

    uint*  ep_tar  = (uint*)(ws + OFF_EPT);
    uint*  ep_src  = (uint*)(ws + OFF_EPS);
    int*   rp_tar  = (int*)(ws + OFF_RPT);
    int*   rp_src  = (int*)(ws + OFF_RPS);
    int*   misc    = (int*)(ws + OFF_MISC);
    uint2* msg_h   = (uint2*)(ws + OFF_MSG);
    uint2* embs1_h = (uint2*)(ws + OFF_EMB);
    uint*  bits1   = (uint*)(ws + OFF_BITS1);
    uint*  bits2   = (uint*)(ws + OFF_BITS2);
    uint2* pois_h  = (uint2*)(ws + OFF_POISH);

    int* cntc_tar = misc;
    int* off_tar  = cntc_tar + NBUCK;
    int* tl_tar   = off_tar + NBUCK + 1;
    int* cntc_src = tl_tar + NBUCK;
    int* off_src  = cntc_src + NBUCK;
    int* tl_src   = off_src + NBUCK + 1;

    uint2* stag_tar = (uint2*)msg_h;   // staging overlays msg_h
    uint2* stag_src = stag_tar + NNZE;

    __shared__ int lds_a[NBUCK];
    __shared__ int lds_b[NBUCK];

    const int B    = gridDim.x;
    const int t    = threadIdx.x;
    const int tid  = blockIdx.x * 256 + t;
    const int nthr = B * 256;
    const int lane = t & 63;
    const int w0   = tid >> 6;
    const int wstr = nthr >> 6;

    // ---- P0: zero counters ; pois->bf16 ; drop masks->bits (all independent)
    for (int i = tid; i < 8192; i += nthr) misc[i] = 0;
    if (full) {
        const float4* pin = (const float4*)pois;
        for (int i = tid; i < NPOIS * DIM / 4; i += nthr) {
            float4 x = pin[i];
            pois_h[i] = make_uint2(pack_bf16(x.x, x.y), pack_bf16(x.z, x.w));
        }
    }
    if (have_bits) {
        const float4* s1 = (const float4*)drop1;
        const float4* s2 = (const float4*)drop2;
        for (int w = tid; w < 1600000; w += nthr) {   // 2*NPOIS*DIM/32 words/array
            uint m1 = 0, m2 = 0;
#pragma unroll
            for (int q = 0; q < 8; ++q) {
                float4 v = s1[(size_t)w * 8 + q];
                m1 |= (v.x != 0.f ? 1u : 0u) << (4 * q);
                m1 |= (v.y != 0.f ? 2u : 0u) << (4 * q);
                m1 |= (v.z != 0.f ? 4u : 0u) << (4 * q);
                m1 |= (v.w != 0.f ? 8u : 0u) << (4 * q);
                float4 u = s2[(size_t)w * 8 + q];
                m2 |= (u.x != 0.f ? 1u : 0u) << (4 * q);
                m2 |= (u.y != 0.f ? 2u : 0u) << (4 * q);
                m2 |= (u.z != 0.f ? 4u : 0u) << (4 * q);
                m2 |= (u.w != 0.f ? 8u : 0u) << (4 * q);
            }
            bits1[w] = m1; bits2[w] = m2;
        }
    }
    grid.sync();

    // ---- P1: coarse histogram (LDS-aggregated, both matrices)
    {
        int per = (NNZE + B - 1) / B;
        int s = blockIdx.x * per, e = min(s + per, NNZE);
        for (int i = t; i < NBUCK; i += 256) { lds_a[i] = 0; lds_b[i] = 0; }
        __syncthreads();
        for (int i = s + t; i < e; i += 256) {
            atomicAdd(&lds_a[tar_rows[i] >> SH_TAR], 1);
            atomicAdd(&lds_b[src_rows[i] >> SH_SRC], 1);
        }
        __syncthreads();
        for (int i = t; i < NBUCK; i += 256) {
            if (lds_a[i]) atomicAdd(&cntc_tar[i], lds_a[i]);
            if (lds_b[i]) atomicAdd(&cntc_src[i], lds_b[i]);
        }
    }
    grid.sync();

    // ---- P2: exclusive scan of both coarse histograms (block 0)
    if (blockIdx.x == 0) {
        for (int sel = 0; sel < 2; ++sel) {
            const int* c = sel ? cntc_src : cntc_tar;
            int* off = sel ? off_src : off_tar;
            int* tl  = sel ? tl_src : tl_tar;
            int carry = 0;
            for (int base = 0; base < NBUCK; base += 256) {
                int i = base + t;
                int v = (i < NBUCK) ? c[i] : 0;
                lds_a[t] = v;
                __syncthreads();
                for (int o = 1; o < 256; o <<= 1) {
                    int x = (t >= o) ? lds_a[t - o] : 0;
                    __syncthreads();
                    lds_a[t] += x;
                    __syncthreads();
                }
                int excl = carry + lds_a[t] - v;
                if (i < NBUCK) { off[i] = excl; tl[i] = excl; }
                carry += lds_a[255];
                __syncthreads();
            }
            if (t == 0) off[NBUCK] = carry;
            __syncthreads();
        }
    }
    grid.sync();

    // ---- P3: stage edges into bucket extents (512 chunks of 6250)
    for (int c = blockIdx.x; c < 512; c += B) {
        bool is_src = c >= 256;
        int blk = c & 255;
        const int* rows = is_src ? src_rows : tar_rows;
        const int* cols = is_src ? src_cols : tar_cols;
        const float* vals = is_src ? src_vals : tar_vals;
        int* tails = is_src ? tl_src : tl_tar;
        uint2* stag = is_src ? stag_src : stag_tar;
        const int SH = is_src ? SH_SRC : SH_TAR;
        int s = blk * CHUNK, e = min(s + CHUNK, NNZE);
        for (int i = t; i < NBUCK; i += 256) lds_a[i] = 0;
        __syncthreads();
        for (int i = s + t; i < e; i += 256) atomicAdd(&lds_a[rows[i] >> SH], 1);
        __syncthreads();
        for (int i = t; i < NBUCK; i += 256) {
            int cc = lds_a[i];
            lds_b[i] = cc ? atomicAdd(&tails[i], cc) : 0;
            lds_a[i] = 0;   // reuse as intra-block tail
        }
        __syncthreads();
        for (int i = s + t; i < e; i += 256) {
            int r = rows[i];
            int b = r >> SH;
            int pos = lds_b[b] + atomicAdd(&lds_a[b], 1);
            uint uv = __float_as_uint(vals[i]);
            uv += 0x7fffu + ((uv >> 16) & 1u);   // RNE to bf16 (val>=0)
            stag[pos] = make_uint2((uint)r, ((uint)cols[i] << 15) | ((uv >> 16) & 0x7fffu));
        }
        __syncthreads();
    }
    grid.sync();

    // ---- P4: finalize per bucket (build rp; write packed ep sequentially)
    for (int c = blockIdx.x; c < 2 * NBUCK; c += B) {
        bool is_src = c >= NBUCK;
        int b = is_src ? c - NBUCK : c;
        const uint2* stag = is_src ? stag_src : stag_tar;
        const int* off = is_src ? off_src : off_tar;
        int* rp = is_src ? rp_src : rp_tar;
        uint* ep = is_src ? ep_src : ep_tar;
        const int SH = is_src ? SH_SRC : SH_TAR;
        const int RPB = 1 << SH;
        const int nrows = is_src ? NPOIS : NHYP;
        int base = off[b];
        int n = off[b + 1] - base;
        int r0 = b << SH;
        for (int i = t; i < RPB; i += 256) lds_a[i] = 0;
        __syncthreads();
        for (int i = t; i < n; i += 256)
            atomicAdd(&lds_a[(int)stag[base + i].x - r0], 1);
        __syncthreads();
        if (t == 0) {
            int run = 0;
            for (int i = 0; i < RPB; ++i) { lds_b[i] = run; run += lds_a[i]; }
        }
        __syncthreads();
        for (int i = t; i < RPB; i += 256) {
            int rg = r0 + i;
            if (rg < nrows) rp[rg] = base + lds_b[i];
        }
        for (int i = t; i < RPB; i += 256) lds_a[i] = 0;
        __syncthreads();
        for (int i = t; i < n; i += 256) {
            uint2 rec = stag[base + i];
            int rl = (int)rec.x - r0;
            int slot = lds_b[rl] + atomicAdd(&lds_a[rl], 1);
            ep[base + slot] = rec.y;
        }
        __syncthreads();
    }
    if (blockIdx.x == 0 && t == 0) { rp_tar[NHYP] = NNZE; rp_src[NPOIS] = NNZE; }
    grid.sync();

    // ---- P5: msg = HG_tar @ pois  (grid-stride waves)
    if (full) {
        for (int r = w0; r < NHYP; r += wstr) {
            int row = __builtin_amdgcn_readfirstlane(r);
            float4 a = gather_h(rp_tar, ep_tar, pois_h, row, lane);
            msg_h[(size_t)row * (DIM / 4) + lane] =
                make_uint2(pack_bf16(a.x, a.y), pack_bf16(a.z, a.w));
        }
    } else {
        for (int r = w0; r < NHYP; r += wstr) {
            int row = __builtin_amdgcn_readfirstlane(r);
            float4 a = gather_f(rp_tar, ep_tar, (const float4*)pois, row, lane);
            msg_h[(size_t)row * (DIM / 4) + lane] =
                make_uint2(pack_bf16(a.x, a.y), pack_bf16(a.z, a.w));
        }
    }
    grid.sync();

    // ---- P6: embs1 = epi1(HG_src @ msg)
    {
        const float4* d1 = (const float4*)drop1;
        const float4* d2 = (const float4*)drop2;
        for (int r = w0; r < NPOIS; r += wstr) {
            int row = __builtin_amdgcn_readfirstlane(r);
            size_t idx = (size_t)row * (DIM / 4) + lane;
            float4 a, b;
            if (have_bits) { a = drop4(bits1, row, lane); b = drop4(bits2, row, lane); }
            else           { a = d1[idx]; b = d2[idx]; }
            float4 p = full ? unpack_h(pois_h[idx]) : ((const float4*)pois)[idx];
            float4 m = gather_h(rp_src, ep_src, msg_h, row, lane);
            float4 o;
            o.x = (fmaxf(m.x, 0.f) * a.x + p.x) * b.x;
            o.y = (fmaxf(m.y, 0.f) * a.y + p.y) * b.y;
            o.z = (fmaxf(m.z, 0.f) * a.z + p.z) * b.z;
            o.w = (fmaxf(m.w, 0.f) * a.w + p.w) * b.w;
            embs1_h[idx] = make_uint2(pack_bf16(o.x, o.y), pack_bf16(o.z, o.w));
        }
    }
    grid.sync();

    // ---- P7: msg = HG_tar @ embs1
    for (int r = w0; r < NHYP; r += wstr) {
        int row = __builtin_amdgcn_readfirstlane(r);
        float4 a = gather_h(rp_tar, ep_tar, embs1_h, row, lane);
        msg_h[(size_t)row * (DIM / 4) + lane] =
            make_uint2(pack_bf16(a.x, a.y), pack_bf16(a.z, a.w));
    }
    grid.sync();

    // ---- P8: final epilogue + softmax combine -> f32 out
    {
        float t0 = attn[0], t1 = attn[1], t2 = attn[2];
        float mx = fmaxf(t0, fmaxf(t1, t2));
        float e0 = __expf(t0 - mx), e1 = __expf(t1 - mx), e2 = __expf(t2 - mx);
        float inv = 1.f / (e0 + e1 + e2);
        float wt0 = e0 * inv, wt1 = e1 * inv, wt2 = e2 * inv;
        const float4* d1 = (const float4*)(drop1 + (size_t)NPOIS * DIM);
        const float4* d2 = (const float4*)(drop2 + (size_t)NPOIS * DIM);
        const uint* b1 = bits1 + (size_t)NPOIS * 8;
        const uint* b2 = bits2 + (size_t)NPOIS * 8;
        for (int r = w0; r < NPOIS; r += wstr) {
            int row = __builtin_amdgcn_readfirstlane(r);
            size_t idx = (size_t)row * (DIM / 4) + lane;
            float4 a, b;
            if (have_bits) { a = drop4(b1, row, lane); b = drop4(b2, row, lane); }
            else           { a = d1[idx]; b = d2[idx]; }
            float4 p0 = full ? unpack_h(pois_h[idx]) : ((const float4*)pois)[idx];
            float4 p1 = unpack_h(embs1_h[idx]);
            float4 m = gather_h(rp_src, ep_src, msg_h, row, lane);
            float4 o;
            o.x = wt0 * p0.x + wt1 * p1.x + wt2 * ((fmaxf(m.x, 0.f) * a.x + p1.x) * b.x);
            o.y = wt0 * p0.y + wt1 * p1.y + wt2 * ((fmaxf(m.y, 0.f) * a.y + p1.y) * b.y);
            o.z = wt0 * p0.z + wt1 * p1.z + wt2 * ((fmaxf(m.z, 0.f) * a.z + p1.z) * b.z);
            o.w = wt0 * p0.w + wt1 * p1.w + wt2 * ((fmaxf(m.w, 0.f) * a.w + p1.w) * b.w);
            out[idx] = o;
        }
    }
}

// =====================================================================
// FALLBACK: round-6 multi-kernel path (verbatim behavior, proven passing)
// =====================================================================
__global__ __launch_bounds__(256) void to_h_kernel(
    const float4* __restrict__ in, uint2* __restrict__ out, int n4)
{
    int stride = gridDim.x * blockDim.x;
    for (int i = blockIdx.x * blockDim.x + threadIdx.x; i < n4; i += stride) {
        float4 x = in[i];
        out[i] = make_uint2(pack_bf16(x.x, x.y), pack_bf16(x.z, x.w));
    }
}

__global__ __launch_bounds__(256) void drop_bits_kernel(
    const float4* __restrict__ d1, const float4* __restrict__ d2,
    uint* __restrict__ o1, uint* __restrict__ o2, int nw)
{
    int t = blockIdx.x * blockDim.x + threadIdx.x;
    if (t >= 2 * nw) return;
    const float4* src = (t < nw) ? d1 : d2;
    uint* dst = (t < nw) ? o1 : o2;
    int w = (t < nw) ? t : t - nw;
    uint m = 0;
#pragma unroll
    for (int q = 0; q < 8; ++q) {
        float4 v = src[(size_t)w * 8 + q];
        m |= (v.x != 0.f ? 1u : 0u) << (4 * q);
        m |= (v.y != 0.f ? 2u : 0u) << (4 * q);
        m |= (v.z != 0.f ? 4u : 0u) << (4 * q);
        m |= (v.w != 0.f ? 8u : 0u) << (4 * q);
    }
    dst[w] = m;
}

__global__ __launch_bounds__(256) void hist_coarse(
    const int* __restrict__ tr, const int* __restrict__ sr,
    int* __restrict__ c_tar, int* __restrict__ c_src, int nnz)
{
    __shared__ int lt[NBUCK], ls[NBUCK];
    int t = threadIdx.x;
    int s = blockIdx.x * CHUNK, e = min(s + CHUNK, nnz);
    for (int i = t; i < NBUCK; i += 256) { lt[i] = 0; ls[i] = 0; }
    __syncthreads();
    for (int i = s + t; i < e; i += 256) {
        atomicAdd(&lt[tr[i] >> SH_TAR], 1);
        atomicAdd(&ls[sr[i] >> SH_SRC], 1);
    }
    __syncthreads();
    for (int i = t; i < NBUCK; i += 256) {
        if (lt[i]) atomicAdd(&c_tar[i], lt[i]);
        if (ls[i]) atomicAdd(&c_src[i], ls[i]);
    }
}

__global__ __launch_bounds__(256) void scan_offsets(
    const int* __restrict__ c_tar, const int* __restrict__ c_src,
    int* __restrict__ off_tar, int* __restrict__ tl_tar,
    int* __restrict__ off_src, int* __restrict__ tl_src)
{
    __shared__ int lds[256];
    int t = threadIdx.x;
    for (int sel = 0; sel < 2; ++sel) {
        const int* c = sel ? c_src : c_tar;
        int* off = sel ? off_src : off_tar;
        int* tl  = sel ? tl_src : tl_tar;
        int carry = 0;
        for (int base = 0; base < NBUCK; base += 256) {
            int i = base + t;
            int v = (i < NBUCK) ? c[i] : 0;
            lds[t] = v;
            __syncthreads();
            for (int o = 1; o < 256; o <<= 1) {
                int x = (t >= o) ? lds[t - o] : 0;
                __syncthreads();
                lds[t] += x;
                __syncthreads();
            }
            int excl = carry + lds[t] - v;
            if (i < NBUCK) { off[i] = excl; tl[i] = excl; }
            carry += lds[255];
            __syncthreads();
        }
        if (t == 0) off[NBUCK] = carry;
        __syncthreads();
    }
}

__global__ __launch_bounds__(256) void csr_stage(
    const int* __restrict__ tar_rows, const int* __restrict__ tar_cols,
    const float* __restrict__ tar_vals,
    const int* __restrict__ src_rows, const int* __restrict__ src_cols,
    const float* __restrict__ src_vals,
    int* __restrict__ tl_tar, uint2* __restrict__ stag_tar,
    int* __restrict__ tl_src, uint2* __restrict__ stag_src, int nnz)
{
    __shared__ int lh[NBUCK];
    __shared__ int lbase[NBUCK];
    int t = threadIdx.x;
    bool is_src = blockIdx.x >= 256;
    int blk = is_src ? blockIdx.x - 256 : blockIdx.x;
    const int* rows = is_src ? src_rows : tar_rows;
    const int* cols = is_src ? src_cols : tar_cols;
    const float* vals = is_src ? src_vals : tar_vals;
    int* tails = is_src ? tl_src : tl_tar;
    uint2* stag = is_src ? stag_src : stag_tar;
    const int SH = is_src ? SH_SRC : SH_TAR;

    int s = blk * CHUNK, e = min(s + CHUNK, nnz);
    for (int i = t; i < NBUCK; i += 256) lh[i] = 0;
    __syncthreads();
    for (int i = s + t; i < e; i += 256) atomicAdd(&lh[rows[i] >> SH], 1);
    __syncthreads();
    for (int i = t; i < NBUCK; i += 256) {
        int c = lh[i];
        lbase[i] = c ? atomicAdd(&tails[i], c) : 0;
        lh[i] = 0;
    }
    __syncthreads();
    for (int i = s + t; i < e; i += 256) {
        int r = rows[i];
        int b = r >> SH;
        int pos = lbase[b] + atomicAdd(&lh[b], 1);
        uint uv = __float_as_uint(vals[i]);
        uv += 0x7fffu + ((uv >> 16) & 1u);
        stag[pos] = make_uint2((uint)r, ((uint)cols[i] << 15) | ((uv >> 16) & 0x7fffu));
    }
}

__global__ __launch_bounds__(256) void csr_finalize(
    const uint2* __restrict__ stag_tar, const int* __restrict__ off_tar,
    int* __restrict__ rp_tar, uint* __restrict__ ep_tar,
    const uint2* __restrict__ stag_src, const int* __restrict__ off_src,
    int* __restrict__ rp_src, uint* __restrict__ ep_src, int nnz)
{
    __shared__ uint2 recs[4096];
    __shared__ int lhist[128];
    __shared__ int lbase[129];
    bool is_src = blockIdx.x >= NBUCK;
    int b = is_src ? blockIdx.x - NBUCK : blockIdx.x;
    const uint2* stag = is_src ? stag_src : stag_tar;
    const int* off = is_src ? off_src : off_tar;
    int* rp = is_src ? rp_src : rp_tar;
    uint* ep = is_src ? ep_src : ep_tar;
    const int SH = is_src ? SH_SRC : SH_TAR;
    const int RPB = 1 << SH;
    const int nrows = is_src ? NPOIS : NHYP;
    int t = threadIdx.x;
    int base = off[b];
    int n = off[b + 1] - base;
    int r0 = b << SH;

    for (int i = t; i < RPB; i += 256) lhist[i] = 0;
    __syncthreads();
    bool fit = (n <= 4096);
    for (int i = t; i < n; i += 256) {
        uint2 rec = stag[base + i];
        if (fit) recs[i] = rec;
        atomicAdd(&lhist[(int)rec.x - r0], 1);
    }
    __syncthreads();
    if (t == 0) {
        int run = 0;
        for (int i = 0; i < RPB; ++i) { lbase[i] = run; run += lhist[i]; }
        lbase[RPB] = run;
    }
    __syncthreads();
    for (int i = t; i < RPB; i += 256) {
        int rg = r0 + i;
        if (rg < nrows) rp[rg] = base + lbase[i];
    }
    if (b == 0 && t == 0) rp[nrows] = nnz;
    for (int i = t; i < RPB; i += 256) lhist[i] = 0;
    __syncthreads();
    for (int i = t; i < n; i += 256) {
        uint2 rec = fit ? recs[i] : stag[base + i];
        int rl = (int)rec.x - r0;
        int slot = lbase[rl] + atomicAdd(&lhist[rl], 1);
        ep[base + slot] = rec.y;
    }
}

template <bool BF16D>
__global__ __launch_bounds__(256) void spmm_to_h(
    const int* __restrict__ rp, const uint* __restrict__ ep,
    const void* __restrict__ dense, uint2* __restrict__ out_h, int nrows)
{
    int wid  = (blockIdx.x * blockDim.x + threadIdx.x) >> 6;
    int lane = threadIdx.x & 63;
    if (wid >= nrows) return;
    int row = __builtin_amdgcn_readfirstlane(wid);
    float4 a = BF16D ? gather_h(rp, ep, (const uint2*)dense, row, lane)
                     : gather_f(rp, ep, (const float4*)dense, row, lane);
    out_h[(size_t)row * (DIM / 4) + lane] = make_uint2(pack_bf16(a.x, a.y), pack_bf16(a.z, a.w));
}

template <bool PH, bool BITS>
__global__ __launch_bounds__(256) void spmm_epi1(
    const int* __restrict__ rp, const uint* __restrict__ ep,
    const uint2* __restrict__ msg_h,
    const uint2* __restrict__ pois_h, const float4* __restrict__ pois_f,
    const float4* __restrict__ d1, const float4* __restrict__ d2,
    const uint* __restrict__ bm1, const uint* __restrict__ bm2,
    uint2* __restrict__ out_h, int nrows)
{
    int wid  = (blockIdx.x * blockDim.x + threadIdx.x) >> 6;
    int lane = threadIdx.x & 63;
    if (wid >= nrows) return;
    int row = __builtin_amdgcn_readfirstlane(wid);
    size_t idx = (size_t)row * (DIM / 4) + lane;
    float4 a, b;
    if (BITS) { a = drop4(bm1, row, lane); b = drop4(bm2, row, lane); }
    else      { a = d1[idx]; b = d2[idx]; }
    float4 p = PH ? unpack_h(pois_h[idx]) : pois_f[idx];
    float4 m = gather_h(rp, ep, msg_h, row, lane);
    float4 r;
    r.x = (fmaxf(m.x, 0.f) * a.x + p.x) * b.x;
    r.y = (fmaxf(m.y, 0.f) * a.y + p.y) * b.y;
    r.z = (fmaxf(m.z, 0.f) * a.z + p.z) * b.z;
    r.w = (fmaxf(m.w, 0.f) * a.w + p.w) * b.w;
    out_h[idx] = make_uint2(pack_bf16(r.x, r.y), pack_bf16(r.z, r.w));
}

template <bool PH, bool BITS>
__global__ __launch_bounds__(256) void spmm_final(
    const int* __restrict__ rp, const uint* __restrict__ ep,
    const uint2* __restrict__ msg_h,
    const uint2* __restrict__ pois_h, const float4* __restrict__ pois_f,
    const uint2* __restrict__ embs1_h,
    const float4* __restrict__ d1, const float4* __restrict__ d2,
    const uint* __restrict__ bm1, const uint* __restrict__ bm2,
    const float* __restrict__ attn, float4* __restrict__ out, int nrows)
{
    int wid  = (blockIdx.x * blockDim.x + threadIdx.x) >> 6;
    int lane = threadIdx.x & 63;
    if (wid >= nrows) return;
    int row = __builtin_amdgcn_readfirstlane(wid);

    float a0 = attn[0], a1 = attn[1], a2 = attn[2];
    float mx = fmaxf(a0, fmaxf(a1, a2));
    float e0 = __expf(a0 - mx), e1 = __expf(a1 - mx), e2 = __expf(a2 - mx);
    float inv = 1.f / (e0 + e1 + e2);
    float w0 = e0 * inv, w1 = e1 * inv, w2 = e2 * inv;

    size_t idx = (size_t)row * (DIM / 4) + lane;
    float4 a, b;
    if (BITS) { a = drop4(bm1, row, lane); b = drop4(bm2, row, lane); }
    else      { a = d1[idx]; b = d2[idx]; }
    float4 p0 = PH ? unpack_h(pois_h[idx]) : pois_f[idx];
    float4 p1 = unpack_h(embs1_h[idx]);
    float4 m = gather_h(rp, ep, msg_h, row, lane);
    float4 r;
    r.x = w0 * p0.x + w1 * p1.x + w2 * ((fmaxf(m.x, 0.f) * a.x + p1.x) * b.x);
    r.y = w0 * p0.y + w1 * p1.y + w2 * ((fmaxf(m.y, 0.f) * a.y + p1.y) * b.y);
    r.z = w0 * p0.z + w1 * p1.z + w2 * ((fmaxf(m.z, 0.f) * a.z + p1.z) * b.z);
    r.w = w0 * p0.w + w1 * p1.w + w2 * ((fmaxf(m.w, 0.f) * a.w + p1.w) * b.w);
    out[idx] = r;
}

// ---------- launch ----------
extern "C" void kernel_launch(void* const* d_in, const int* in_sizes, int n_in,
                              void* d_out, int out_size, void* d_ws, size_t ws_size,
                              hipStream_t stream)
{
    const float* pois     = (const float*)d_in[0];
    const float* tar_vals = (const float*)d_in[1];
    const float* src_vals = (const float*)d_in[2];
    const float* attn     = (const float*)d_in[3];
    const float* drop1    = (const float*)d_in[4];
    const float* drop2    = (const float*)d_in[5];
    const int*   tar_rows = (const int*)d_in[6];
    const int*   tar_cols = (const int*)d_in[7];
    const int*   src_rows = (const int*)d_in[8];
    const int*   src_cols = (const int*)d_in[9];
    float4* out = (float4*)d_out;
    char* ws = (char*)d_ws;

    const size_t ptn = (size_t)NPOIS * DIM;
    int have_bits = ws_size >= (size_t)NEED_BITS ? 1 : 0;
    int full      = ws_size >= (size_t)NEED_FULL ? 1 : 0;

    // co-resident grid size for the cooperative launch (query once)
    static int nblk = -1;
    if (nblk < 0) {
        int occ = 0;
        hipError_t oe = hipOccupancyMaxActiveBlocksPerMultiprocessor(
            &occ, (const void*)mega, 256, 0);
        if (oe != hipSuccess || occ < 1) nblk = 0;
        else {
            nblk = occ * 256;            // 256 CUs on MI355X
            if (nblk > 2048) nblk = 2048;
        }
    }

    bool done = false;
    if (nblk > 0) {
        void* args[] = {
            (void*)&pois, (void*)&tar_vals, (void*)&src_vals, (void*)&attn,
            (void*)&drop1, (void*)&drop2, (void*)&tar_rows, (void*)&tar_cols,
            (void*)&src_rows, (void*)&src_cols, (void*)&out, (void*)&ws,
            (void*)&full, (void*)&have_bits };
        hipError_t err = hipLaunchCooperativeKernel(
            (const void*)mega, dim3(nblk), dim3(256), args, 0, stream);
        if (err == hipSuccess) done = true;
    }
    if (done) return;

    // ---------------- fallback: round-6 multi-kernel path ----------------
    uint*  ep_tar  = (uint*)(ws + OFF_EPT);
    uint*  ep_src  = (uint*)(ws + OFF_EPS);
    int*   rp_tar  = (int*)(ws + OFF_RPT);
    int*   rp_src  = (int*)(ws + OFF_RPS);
    int*   misc    = (int*)(ws + OFF_MISC);
    uint2* msg_h   = (uint2*)(ws + OFF_MSG);
    uint2* embs1_h = (uint2*)(ws + OFF_EMB);
    uint*  bits1   = (uint*)(ws + OFF_BITS1);
    uint*  bits2   = (uint*)(ws + OFF_BITS2);
    uint2* pois_h  = (uint2*)(ws + OFF_POISH);

    int* cntc_tar = misc;
    int* off_tar  = cntc_tar + NBUCK;
    int* tl_tar   = off_tar + NBUCK + 1;
    int* cntc_src = tl_tar + NBUCK;
    int* off_src  = cntc_src + NBUCK;
    int* tl_src   = off_src + NBUCK + 1;

    uint2* stag_tar = (uint2*)msg_h;
    uint2* stag_src = stag_tar + NNZE;

    const int BLK = 256;

    if (full)
        to_h_kernel<<<(int)(ptn / 4 + BLK - 1) / BLK, BLK, 0, stream>>>(
            (const float4*)pois, pois_h, (int)(ptn / 4));

    if (have_bits) {
        int nw = (int)(2 * ptn / 32);
        drop_bits_kernel<<<(2 * nw + BLK - 1) / BLK, BLK, 0, stream>>>(
            (const float4*)drop1, (const float4*)drop2, bits1, bits2, nw);
    }

    hipMemsetAsync(misc, 0, 32768, stream);
    hist_coarse<<<256, BLK, 0, stream>>>(tar_rows, src_rows, cntc_tar, cntc_src, NNZE);
    scan_offsets<<<1, BLK, 0, stream>>>(cntc_tar, cntc_src, off_tar, tl_tar, off_src, tl_src);
    csr_stage<<<512, BLK, 0, stream>>>(
        tar_rows, tar_cols, tar_vals, src_rows, src_cols, src_vals,
        tl_tar, stag_tar, tl_src, stag_src, NNZE);
    csr_finalize<<<2 * NBUCK, BLK, 0, stream>>>(
        stag_tar, off_tar, rp_tar, ep_tar,
        stag_src, off_src, rp_src, ep_src, NNZE);

    const int gb_hyp = NHYP / 4;
    const int gb_poi = NPOIS / 4;

    const float4* d1_l0 = (const float4*)drop1;
    const float4* d2_l0 = (const float4*)drop2;
    const float4* d1_l1 = (const float4*)(drop1 + ptn);
    const float4* d2_l1 = (const float4*)(drop2 + ptn);
    const uint* b1_l0 = bits1;
    const uint* b2_l0 = bits2;
    const uint* b1_l1 = bits1 + (size_t)NPOIS * 8;
    const uint* b2_l1 = bits2 + (size_t)NPOIS * 8;

    if (full)
        spmm_to_h<true><<<gb_hyp, BLK, 0, stream>>>(rp_tar, ep_tar, pois_h, msg_h, NHYP);
    else
        spmm_to_h<false><<<gb_hyp, BLK, 0, stream>>>(rp_tar, ep_tar, pois, msg_h, NHYP);

    if (full && have_bits)
        spmm_epi1<true, true><<<gb_poi, BLK, 0, stream>>>(
            rp_src, ep_src, msg_h, pois_h, (const float4*)pois,
            d1_l0, d2_l0, b1_l0, b2_l0, embs1_h, NPOIS);
    else if (full)
        spmm_epi1<true, false><<<gb_poi, BLK, 0, stream>>>(
            rp_src, ep_src, msg_h, pois_h, (const float4*)pois,
            d1_l0, d2_l0, b1_l0, b2_l0, embs1_h, NPOIS);
    else if (have_bits)
        spmm_epi1<false, true><<<gb_poi, BLK, 0, stream>>>(
            rp_src, ep_src, msg_h, pois_h, (const float4*)pois,
            d1_l0, d2_l0, b1_l0, b2_l0, embs1_h, NPOIS);
    else
        spmm_epi1<false, false><<<gb_poi, BLK, 0, stream>>>(
            rp_src, ep_src, msg_h, pois_h, (const float4*)pois,
            d1_l0, d2_l0, b1_l0, b2_l0, embs1_h, NPOIS);

    spmm_to_h<true><<<gb_hyp, BLK, 0, stream>>>(rp_tar, ep_tar, embs1_h, msg_h, NHYP);

    if (full && have_bits)
        spmm_final<true, true><<<gb_poi, BLK, 0, stream>>>(
            rp_src, ep_src, msg_h, pois_h, (const float4*)pois, embs1_h,
            d1_l1, d2_l1, b1_l1, b2_l1, attn, out, NPOIS);
    else if (full)
        spmm_final<true, false><<<gb_poi, BLK, 0, stream>>>(
            rp_src, ep_src, msg_h, pois_h, (const float4*)pois, embs1_h,
            d1_l1, d2_l1, b1_l1, b2_l1, attn, out, NPOIS);
    else if (have_bits)
        spmm_final<false, true><<<gb_poi, BLK, 0, stream>>>(
            rp_src, ep_src, msg_h, pois_h, (const float4*)pois, embs1_h,
            d1_l1, d2_l1, b1_l1, b2_l1, attn, out, NPOIS);
    else
        spmm_final<false, false><<<gb_poi, BLK, 0, stream>>>(
            rp_src, ep_src, msg_h, pois_h, (const float4*)pois, embs1_h,
            d1_l1, d2_l1, b1_l1, b2_l1, attn, out, NPOIS);
}

// Round 8
// 1058.796 us; speedup vs baseline: 2.0917x; 2.0917x over previous
//
#include <hip/hip_runtime.h>

#define NPOIS 100000
#define NHYP  50000
#define NNZE  1600000
#define DIM   256

// coarse bucket shifts: 782 buckets for both matrices
#define SH_TAR 6    // 64 rows/bucket
#define SH_SRC 7    // 128 rows/bucket
#define NBUCK 782
#define CHUNK 6250  // 256 chunks * 6250 = NNZE exactly

typedef unsigned int uint;

// exact f32 value of the reference's dropout scale 1/(1-0.3)
#define DROP_C ((float)(1.0 / (1.0 - 0.3)))

// ---- workspace byte offsets (identical footprint to proven 154.2 MB layout) ----
#define OFF_EPT   0
#define OFF_EPS   6400000
#define OFF_RPT   12800000
#define OFF_RPS   13000064
#define OFF_MISC  13400128
#define OFF_MSG   13432896              // int8 msg (12.8 MB) ...
#define OFF_SC    26232896              // ... + per-row scales (0.2 MB); region is
                                        //     25.6 MB total (staging overlay needs it)
#define OFF_EMB   39032896
#define OFF_BITS1 90232896
#define OFF_BITS2 96632896
#define OFF_POISH 103032896
#define NEED_BITS 103032896
#define NEED_FULL 154232896

// ---------- bf16 helpers (RNE) ----------
__device__ __forceinline__ uint pack_bf16(float a, float b) {
    uint ua = __float_as_uint(a); ua += 0x7fffu + ((ua >> 16) & 1u);
    uint ub = __float_as_uint(b); ub += 0x7fffu + ((ub >> 16) & 1u);
    return (ua >> 16) | (ub & 0xffff0000u);
}
__device__ __forceinline__ float4 unpack_h(uint2 u) {
    return make_float4(__uint_as_float(u.x << 16), __uint_as_float(u.x & 0xffff0000u),
                       __uint_as_float(u.y << 16), __uint_as_float(u.y & 0xffff0000u));
}

// ---------- gather cores (full-D, batched depth-8, packed 4-B edges) ----------
// row is wave-uniform (readfirstlane) -> edge loads are scalar broadcasts.
// decode: col = u >> 15, val = f32 from bf16 bits (u & 0x7fff) << 16 (val >= 0).
// pad u = 0 -> col 0, val +0.0 (exact no-op) keeps full load depth on tails.
#define GCH 8

__device__ __forceinline__ float4 gather_h(
    const int* __restrict__ rp, const uint* __restrict__ ep,
    const uint2* __restrict__ dh, int row, int lane)
{
    int s = rp[row], e = rp[row + 1];
    float4 acc = {0.f, 0.f, 0.f, 0.f};
    for (int k = s; k < e; k += GCH) {
        uint ev[GCH];
#pragma unroll
        for (int j = 0; j < GCH; ++j)
            ev[j] = (k + j < e) ? ep[k + j] : 0u;
        uint2 x[GCH];
#pragma unroll
        for (int j = 0; j < GCH; ++j)
            x[j] = dh[(size_t)(ev[j] >> 15) * (DIM / 4) + lane];
#pragma unroll
        for (int j = 0; j < GCH; ++j) {
            float vv = __uint_as_float((ev[j] & 0x7fffu) << 16);
            acc.x += vv * __uint_as_float(x[j].x << 16);
            acc.y += vv * __uint_as_float(x[j].x & 0xffff0000u);
            acc.z += vv * __uint_as_float(x[j].y << 16);
            acc.w += vv * __uint_as_float(x[j].y & 0xffff0000u);
        }
    }
    return acc;
}

__device__ __forceinline__ float4 gather_f(
    const int* __restrict__ rp, const uint* __restrict__ ep,
    const float4* __restrict__ d4, int row, int lane)
{
    int s = rp[row], e = rp[row + 1];
    float4 acc = {0.f, 0.f, 0.f, 0.f};
    for (int k = s; k < e; k += GCH) {
        uint ev[GCH];
#pragma unroll
        for (int j = 0; j < GCH; ++j)
            ev[j] = (k + j < e) ? ep[k + j] : 0u;
        float4 x[GCH];
#pragma unroll
        for (int j = 0; j < GCH; ++j)
            x[j] = d4[(size_t)(ev[j] >> 15) * (DIM / 4) + lane];
#pragma unroll
        for (int j = 0; j < GCH; ++j) {
            float vv = __uint_as_float((ev[j] & 0x7fffu) << 16);
            acc.x += vv * x[j].x;
            acc.y += vv * x[j].y;
            acc.z += vv * x[j].z;
            acc.w += vv * x[j].w;
        }
    }
    return acc;
}

// int8-with-per-row-scale gather: mq[row][256] int8, sc[row] = step.
// 4 B/lane gather (4x less than bf16); decode is bfe+cvt+fmac per elem
// (same VALU as bf16 unpack); step folds into the per-edge vv multiply.
__device__ __forceinline__ float4 gather_q(
    const int* __restrict__ rp, const uint* __restrict__ ep,
    const uint* __restrict__ mq, const float* __restrict__ sc,
    int row, int lane)
{
    int s = rp[row], e = rp[row + 1];
    float4 acc = {0.f, 0.f, 0.f, 0.f};
    for (int k = s; k < e; k += GCH) {
        uint ev[GCH];
#pragma unroll
        for (int j = 0; j < GCH; ++j)
            ev[j] = (k + j < e) ? ep[k + j] : 0u;
        uint x[GCH]; float st[GCH];
#pragma unroll
        for (int j = 0; j < GCH; ++j) {
            uint c = ev[j] >> 15;
            x[j]  = mq[(size_t)c * 64 + lane];
            st[j] = sc[c];
        }
#pragma unroll
        for (int j = 0; j < GCH; ++j) {
            float vv = __uint_as_float((ev[j] & 0x7fffu) << 16) * st[j];
            acc.x += vv * (float)((int)(x[j] << 24) >> 24);
            acc.y += vv * (float)((int)(x[j] << 16) >> 24);
            acc.z += vv * (float)((int)(x[j] <<  8) >> 24);
            acc.w += vv * (float)((int)x[j] >> 24);
        }
    }
    return acc;
}

// drop-mask bits: word = row*8 + (lane>>3), bits (lane&7)*4 .. +3
__device__ __forceinline__ float4 drop4(const uint* __restrict__ bm, int row, int lane)
{
    uint m = bm[(size_t)row * 8 + (lane >> 3)] >> ((lane & 7) * 4);
    return make_float4((m & 1u) ? DROP_C : 0.f, (m & 2u) ? DROP_C : 0.f,
                       (m & 4u) ? DROP_C : 0.f, (m & 8u) ? DROP_C : 0.f);
}

// ---------- fused prep: hist_coarse + drop_bits + to_h in one launch ----------
// blocks [0,256): coarse histogram chunks; next 12500 (if bits): mask->bit pass;
// rest 25000 (if full): pois f32->bf16. All three are independent.
__global__ __launch_bounds__(256) void prep_kernel(
    const float4* __restrict__ pois, uint2* __restrict__ pois_h,
    const float4* __restrict__ d1, const float4* __restrict__ d2,
    uint* __restrict__ o1, uint* __restrict__ o2,
    const int* __restrict__ tr, const int* __restrict__ sr,
    int* __restrict__ c_tar, int* __restrict__ c_src,
    int full, int have_bits)
{
    __shared__ int lt[NBUCK], ls[NBUCK];
    int b = blockIdx.x, t = threadIdx.x;
    if (b < 256) {
        int s = b * CHUNK, e = s + CHUNK;
        for (int i = t; i < NBUCK; i += 256) { lt[i] = 0; ls[i] = 0; }
        __syncthreads();
        for (int i = s + t; i < e; i += 256) {
            atomicAdd(&lt[tr[i] >> SH_TAR], 1);
            atomicAdd(&ls[sr[i] >> SH_SRC], 1);
        }
        __syncthreads();
        for (int i = t; i < NBUCK; i += 256) {
            if (lt[i]) atomicAdd(&c_tar[i], lt[i]);
            if (ls[i]) atomicAdd(&c_src[i], ls[i]);
        }
        return;
    }
    int base_bits = 256;
    if (have_bits && b < base_bits + 12500) {
        const int nw = 1600000;                 // words per array (2 layers)
        int w = (b - base_bits) * 256 + t;      // [0, 3.2M)
        if (w < 2 * nw) {
            const float4* src = (w < nw) ? d1 : d2;
            uint* dst = (w < nw) ? o1 : o2;
            int ww = (w < nw) ? w : w - nw;
            uint m = 0;
#pragma unroll
            for (int q = 0; q < 8; ++q) {
                float4 v = src[(size_t)ww * 8 + q];
                m |= (v.x != 0.f ? 1u : 0u) << (4 * q);
                m |= (v.y != 0.f ? 2u : 0u) << (4 * q);
                m |= (v.z != 0.f ? 4u : 0u) << (4 * q);
                m |= (v.w != 0.f ? 8u : 0u) << (4 * q);
            }
            dst[ww] = m;
        }
        return;
    }
    if (full) {
        int base_toh = 256 + (have_bits ? 12500 : 0);
        int i = (b - base_toh) * 256 + t;       // exactly 6.4M float4s
        if (i < NPOIS * (DIM / 4)) {
            float4 x = pois[i];
            pois_h[i] = make_uint2(pack_bf16(x.x, x.y), pack_bf16(x.z, x.w));
        }
    }
}

// ---------- CSR build v2 (round-5/6 verified) ----------
__global__ __launch_bounds__(256) void scan_offsets(
    const int* __restrict__ c_tar, const int* __restrict__ c_src,
    int* __restrict__ off_tar, int* __restrict__ tl_tar,
    int* __restrict__ off_src, int* __restrict__ tl_src)
{
    __shared__ int lds[256];
    int t = threadIdx.x;
    for (int sel = 0; sel < 2; ++sel) {
        const int* c = sel ? c_src : c_tar;
        int* off = sel ? off_src : off_tar;
        int* tl  = sel ? tl_src : tl_tar;
        int carry = 0;
        for (int base = 0; base < NBUCK; base += 256) {
            int i = base + t;
            int v = (i < NBUCK) ? c[i] : 0;
            lds[t] = v;
            __syncthreads();
            for (int o = 1; o < 256; o <<= 1) {
                int x = (t >= o) ? lds[t - o] : 0;
                __syncthreads();
                lds[t] += x;
                __syncthreads();
            }
            int excl = carry + lds[t] - v;
            if (i < NBUCK) { off[i] = excl; tl[i] = excl; }
            carry += lds[255];
            __syncthreads();
        }
        if (t == 0) off[NBUCK] = carry;
        __syncthreads();
    }
}

__global__ __launch_bounds__(256) void csr_stage(
    const int* __restrict__ tar_rows, const int* __restrict__ tar_cols,
    const float* __restrict__ tar_vals,
    const int* __restrict__ src_rows, const int* __restrict__ src_cols,
    const float* __restrict__ src_vals,
    int* __restrict__ tl_tar, uint2* __restrict__ stag_tar,
    int* __restrict__ tl_src, uint2* __restrict__ stag_src, int nnz)
{
    __shared__ int lh[NBUCK];
    __shared__ int lbase[NBUCK];
    int t = threadIdx.x;
    bool is_src = blockIdx.x >= 256;
    int blk = is_src ? blockIdx.x - 256 : blockIdx.x;
    const int* rows = is_src ? src_rows : tar_rows;
    const int* cols = is_src ? src_cols : tar_cols;
    const float* vals = is_src ? src_vals : tar_vals;
    int* tails = is_src ? tl_src : tl_tar;
    uint2* stag = is_src ? stag_src : stag_tar;
    const int SH = is_src ? SH_SRC : SH_TAR;

    int s = blk * CHUNK, e = min(s + CHUNK, nnz);
    for (int i = t; i < NBUCK; i += 256) lh[i] = 0;
    __syncthreads();
    for (int i = s + t; i < e; i += 256) atomicAdd(&lh[rows[i] >> SH], 1);
    __syncthreads();
    for (int i = t; i < NBUCK; i += 256) {
        int c = lh[i];
        lbase[i] = c ? atomicAdd(&tails[i], c) : 0;
        lh[i] = 0;
    }
    __syncthreads();
    for (int i = s + t; i < e; i += 256) {
        int r = rows[i];
        int b = r >> SH;
        int pos = lbase[b] + atomicAdd(&lh[b], 1);
        uint uv = __float_as_uint(vals[i]);
        uv += 0x7fffu + ((uv >> 16) & 1u);          // RNE to bf16 (val>=0)
        stag[pos] = make_uint2((uint)r, ((uint)cols[i] << 15) | ((uv >> 16) & 0x7fffu));
    }
}

__global__ __launch_bounds__(256) void csr_finalize(
    const uint2* __restrict__ stag_tar, const int* __restrict__ off_tar,
    int* __restrict__ rp_tar, uint* __restrict__ ep_tar,
    const uint2* __restrict__ stag_src, const int* __restrict__ off_src,
    int* __restrict__ rp_src, uint* __restrict__ ep_src, int nnz)
{
    __shared__ uint2 recs[4096];
    __shared__ int lhist[128];
    __shared__ int lbase[129];
    bool is_src = blockIdx.x >= NBUCK;
    int b = is_src ? blockIdx.x - NBUCK : blockIdx.x;
    const uint2* stag = is_src ? stag_src : stag_tar;
    const int* off = is_src ? off_src : off_tar;
    int* rp = is_src ? rp_src : rp_tar;
    uint* ep = is_src ? ep_src : ep_tar;
    const int SH = is_src ? SH_SRC : SH_TAR;
    const int RPB = 1 << SH;
    const int nrows = is_src ? NPOIS : NHYP;
    int t = threadIdx.x;
    int base = off[b];
    int n = off[b + 1] - base;
    int r0 = b << SH;

    for (int i = t; i < RPB; i += 256) lhist[i] = 0;
    __syncthreads();
    bool fit = (n <= 4096);
    for (int i = t; i < n; i += 256) {
        uint2 rec = stag[base + i];
        if (fit) recs[i] = rec;
        atomicAdd(&lhist[(int)rec.x - r0], 1);
    }
    __syncthreads();
    if (t == 0) {
        int run = 0;
        for (int i = 0; i < RPB; ++i) { lbase[i] = run; run += lhist[i]; }
        lbase[RPB] = run;
    }
    __syncthreads();
    for (int i = t; i < RPB; i += 256) {
        int rg = r0 + i;
        if (rg < nrows) rp[rg] = base + lbase[i];
    }
    if (b == 0 && t == 0) rp[nrows] = nnz;
    for (int i = t; i < RPB; i += 256) lhist[i] = 0;
    __syncthreads();
    for (int i = t; i < n; i += 256) {
        uint2 rec = fit ? recs[i] : stag[base + i];
        int rl = (int)rec.x - r0;
        int slot = lbase[rl] + atomicAdd(&lhist[rl], 1);
        ep[base + slot] = rec.y;
    }
}

// ---------- SpMM kernels ----------
// hyperedge-side SpMM -> int8 msg + per-row scale. BF16D: dense is bf16.
template <bool BF16D>
__global__ __launch_bounds__(256) void spmm_to_h(
    const int* __restrict__ rp, const uint* __restrict__ ep,
    const void* __restrict__ dense, uint* __restrict__ mq,
    float* __restrict__ sc, int nrows)
{
    int wid  = (blockIdx.x * blockDim.x + threadIdx.x) >> 6;
    int lane = threadIdx.x & 63;
    if (wid >= nrows) return;
    int row = __builtin_amdgcn_readfirstlane(wid);
    float4 a = BF16D ? gather_h(rp, ep, (const uint2*)dense, row, lane)
                     : gather_f(rp, ep, (const float4*)dense, row, lane);
    // per-row absmax (wave butterfly) -> int8 quantize, step = max/127
    float am = fmaxf(fmaxf(fabsf(a.x), fabsf(a.y)), fmaxf(fabsf(a.z), fabsf(a.w)));
#pragma unroll
    for (int m = 1; m < 64; m <<= 1) am = fmaxf(am, __shfl_xor(am, m, 64));
    float inv = am > 0.f ? 127.f / am : 0.f;
    int q0 = __float2int_rn(a.x * inv);
    int q1 = __float2int_rn(a.y * inv);
    int q2 = __float2int_rn(a.z * inv);
    int q3 = __float2int_rn(a.w * inv);
    mq[(size_t)row * 64 + lane] =
        (uint)(q0 & 0xff) | ((uint)(q1 & 0xff) << 8) |
        ((uint)(q2 & 0xff) << 16) | ((uint)q3 << 24);
    if (lane == 0) sc[row] = am * (1.f / 127.f);
}

// poi-side SpMM + layer-1 epilogue -> embs1 (bf16).
template <bool PH, bool BITS>
__global__ __launch_bounds__(256) void spmm_epi1(
    const int* __restrict__ rp, const uint* __restrict__ ep,
    const uint* __restrict__ mq, const float* __restrict__ sc,
    const uint2* __restrict__ pois_h, const float4* __restrict__ pois_f,
    const float4* __restrict__ d1, const float4* __restrict__ d2,
    const uint* __restrict__ bm1, const uint* __restrict__ bm2,
    uint2* __restrict__ out_h, int nrows)
{
    int wid  = (blockIdx.x * blockDim.x + threadIdx.x) >> 6;
    int lane = threadIdx.x & 63;
    if (wid >= nrows) return;
    int row = __builtin_amdgcn_readfirstlane(wid);
    size_t idx = (size_t)row * (DIM / 4) + lane;
    float4 a, b;
    if (BITS) { a = drop4(bm1, row, lane); b = drop4(bm2, row, lane); }
    else      { a = d1[idx]; b = d2[idx]; }
    float4 p = PH ? unpack_h(pois_h[idx]) : pois_f[idx];
    float4 m = gather_q(rp, ep, mq, sc, row, lane);
    float4 r;
    r.x = (fmaxf(m.x, 0.f) * a.x + p.x) * b.x;
    r.y = (fmaxf(m.y, 0.f) * a.y + p.y) * b.y;
    r.z = (fmaxf(m.z, 0.f) * a.z + p.z) * b.z;
    r.w = (fmaxf(m.w, 0.f) * a.w + p.w) * b.w;
    out_h[idx] = make_uint2(pack_bf16(r.x, r.y), pack_bf16(r.z, r.w));
}

// poi-side SpMM + layer-2 epilogue + softmax-weighted combine -> f32 out.
template <bool PH, bool BITS>
__global__ __launch_bounds__(256) void spmm_final(
    const int* __restrict__ rp, const uint* __restrict__ ep,
    const uint* __restrict__ mq, const float* __restrict__ sc,
    const uint2* __restrict__ pois_h, const float4* __restrict__ pois_f,
    const uint2* __restrict__ embs1_h,
    const float4* __restrict__ d1, const float4* __restrict__ d2,
    const uint* __restrict__ bm1, const uint* __restrict__ bm2,
    const float* __restrict__ attn, float4* __restrict__ out, int nrows)
{
    int wid  = (blockIdx.x * blockDim.x + threadIdx.x) >> 6;
    int lane = threadIdx.x & 63;
    if (wid >= nrows) return;
    int row = __builtin_amdgcn_readfirstlane(wid);

    float a0 = attn[0], a1 = attn[1], a2 = attn[2];
    float mx = fmaxf(a0, fmaxf(a1, a2));
    float e0 = __expf(a0 - mx), e1 = __expf(a1 - mx), e2 = __expf(a2 - mx);
    float inv = 1.f / (e0 + e1 + e2);
    float w0 = e0 * inv, w1 = e1 * inv, w2 = e2 * inv;

    size_t idx = (size_t)row * (DIM / 4) + lane;
    float4 a, b;
    if (BITS) { a = drop4(bm1, row, lane); b = drop4(bm2, row, lane); }
    else      { a = d1[idx]; b = d2[idx]; }
    float4 p0 = PH ? unpack_h(pois_h[idx]) : pois_f[idx];
    float4 p1 = unpack_h(embs1_h[idx]);
    float4 m = gather_q(rp, ep, mq, sc, row, lane);
    float4 r;
    r.x = w0 * p0.x + w1 * p1.x + w2 * ((fmaxf(m.x, 0.f) * a.x + p1.x) * b.x);
    r.y = w0 * p0.y + w1 * p1.y + w2 * ((fmaxf(m.y, 0.f) * a.y + p1.y) * b.y);
    r.z = w0 * p0.z + w1 * p1.z + w2 * ((fmaxf(m.z, 0.f) * a.z + p1.z) * b.z);
    r.w = w0 * p0.w + w1 * p1.w + w2 * ((fmaxf(m.w, 0.f) * a.w + p1.w) * b.w);
    out[idx] = r;
}

// ---------- launch ----------
extern "C" void kernel_launch(void* const* d_in, const int* in_sizes, int n_in,
                              void* d_out, int out_size, void* d_ws, size_t ws_size,
                              hipStream_t stream)
{
    const float* pois     = (const float*)d_in[0];
    const float* tar_vals = (const float*)d_in[1];
    const float* src_vals = (const float*)d_in[2];
    const float* attn     = (const float*)d_in[3];
    const float* drop1    = (const float*)d_in[4];
    const float* drop2    = (const float*)d_in[5];
    const int*   tar_rows = (const int*)d_in[6];
    const int*   tar_cols = (const int*)d_in[7];
    const int*   src_rows = (const int*)d_in[8];
    const int*   src_cols = (const int*)d_in[9];
    float4* out = (float4*)d_out;
    char* ws = (char*)d_ws;

    const size_t ptn = (size_t)NPOIS * DIM;
    int have_bits = ws_size >= (size_t)NEED_BITS ? 1 : 0;
    int full      = ws_size >= (size_t)NEED_FULL ? 1 : 0;

    uint*  ep_tar  = (uint*)(ws + OFF_EPT);
    uint*  ep_src  = (uint*)(ws + OFF_EPS);
    int*   rp_tar  = (int*)(ws + OFF_RPT);
    int*   rp_src  = (int*)(ws + OFF_RPS);
    int*   misc    = (int*)(ws + OFF_MISC);
    uint*  msg_q   = (uint*)(ws + OFF_MSG);
    float* msg_sc  = (float*)(ws + OFF_SC);
    uint2* embs1_h = (uint2*)(ws + OFF_EMB);
    uint*  bits1   = (uint*)(ws + OFF_BITS1);
    uint*  bits2   = (uint*)(ws + OFF_BITS2);
    uint2* pois_h  = (uint2*)(ws + OFF_POISH);

    int* cntc_tar = misc;
    int* off_tar  = cntc_tar + NBUCK;
    int* tl_tar   = off_tar + NBUCK + 1;
    int* cntc_src = tl_tar + NBUCK;
    int* off_src  = cntc_src + NBUCK;
    int* tl_src   = off_src + NBUCK + 1;

    // staging overlays the 25.6 MB msg region (CSR build precedes msg writes)
    uint2* stag_tar = (uint2*)(ws + OFF_MSG);
    uint2* stag_src = stag_tar + NNZE;

    const int BLK = 256;

    // ---- fused prep (hist + bits + to_h) ----
    hipMemsetAsync(misc, 0, 32768, stream);
    int prep_grid = 256 + (have_bits ? 12500 : 0) + (full ? 25000 : 0);
    prep_kernel<<<prep_grid, BLK, 0, stream>>>(
        (const float4*)pois, pois_h,
        (const float4*)drop1, (const float4*)drop2, bits1, bits2,
        tar_rows, src_rows, cntc_tar, cntc_src, full, have_bits);

    scan_offsets<<<1, BLK, 0, stream>>>(cntc_tar, cntc_src, off_tar, tl_tar, off_src, tl_src);
    csr_stage<<<512, BLK, 0, stream>>>(
        tar_rows, tar_cols, tar_vals, src_rows, src_cols, src_vals,
        tl_tar, stag_tar, tl_src, stag_src, NNZE);
    csr_finalize<<<2 * NBUCK, BLK, 0, stream>>>(
        stag_tar, off_tar, rp_tar, ep_tar,
        stag_src, off_src, rp_src, ep_src, NNZE);

    const int gb_hyp = NHYP / 4;   // 12500 blocks (4 waves each)
    const int gb_poi = NPOIS / 4;  // 25000 blocks

    const float4* d1_l0 = (const float4*)drop1;
    const float4* d2_l0 = (const float4*)drop2;
    const float4* d1_l1 = (const float4*)(drop1 + ptn);
    const float4* d2_l1 = (const float4*)(drop2 + ptn);
    const uint* b1_l0 = bits1;
    const uint* b2_l0 = bits2;
    const uint* b1_l1 = bits1 + (size_t)NPOIS * 8;
    const uint* b2_l1 = bits2 + (size_t)NPOIS * 8;

    // ---- layer 1 ----
    if (full)
        spmm_to_h<true><<<gb_hyp, BLK, 0, stream>>>(rp_tar, ep_tar, pois_h, msg_q, msg_sc, NHYP);
    else
        spmm_to_h<false><<<gb_hyp, BLK, 0, stream>>>(rp_tar, ep_tar, pois, msg_q, msg_sc, NHYP);

    if (full && have_bits)
        spmm_epi1<true, true><<<gb_poi, BLK, 0, stream>>>(
            rp_src, ep_src, msg_q, msg_sc, pois_h, (const float4*)pois,
            d1_l0, d2_l0, b1_l0, b2_l0, embs1_h, NPOIS);
    else if (full)
        spmm_epi1<true, false><<<gb_poi, BLK, 0, stream>>>(
            rp_src, ep_src, msg_q, msg_sc, pois_h, (const float4*)pois,
            d1_l0, d2_l0, b1_l0, b2_l0, embs1_h, NPOIS);
    else if (have_bits)
        spmm_epi1<false, true><<<gb_poi, BLK, 0, stream>>>(
            rp_src, ep_src, msg_q, msg_sc, pois_h, (const float4*)pois,
            d1_l0, d2_l0, b1_l0, b2_l0, embs1_h, NPOIS);
    else
        spmm_epi1<false, false><<<gb_poi, BLK, 0, stream>>>(
            rp_src, ep_src, msg_q, msg_sc, pois_h, (const float4*)pois,
            d1_l0, d2_l0, b1_l0, b2_l0, embs1_h, NPOIS);

    // ---- layer 2 ----
    spmm_to_h<true><<<gb_hyp, BLK, 0, stream>>>(rp_tar, ep_tar, embs1_h, msg_q, msg_sc, NHYP);

    if (full && have_bits)
        spmm_final<true, true><<<gb_poi, BLK, 0, stream>>>(
            rp_src, ep_src, msg_q, msg_sc, pois_h, (const float4*)pois, embs1_h,
            d1_l1, d2_l1, b1_l1, b2_l1, attn, out, NPOIS);
    else if (full)
        spmm_final<true, false><<<gb_poi, BLK, 0, stream>>>(
            rp_src, ep_src, msg_q, msg_sc, pois_h, (const float4*)pois, embs1_h,
            d1_l1, d2_l1, b1_l1, b2_l1, attn, out, NPOIS);
    else if (have_bits)
        spmm_final<false, true><<<gb_poi, BLK, 0, stream>>>(
            rp_src, ep_src, msg_q, msg_sc, pois_h, (const float4*)pois, embs1_h,
            d1_l1, d2_l1, b1_l1, b2_l1, attn, out, NPOIS);
    else
        spmm_final<false, false><<<gb_poi, BLK, 0, stream>>>(
            rp_src, ep_src, msg_q, msg_sc, pois_h, (const float4*)pois, embs1_h,
            d1_l1, d2_l1, b1_l1, b2_l1, attn, out, NPOIS);
}